// Round 7
// baseline (412.926 us; speedup 1.0000x reference)
//
#include <hip/hip_runtime.h>
#include <hip/hip_bf16.h>
#include <math.h>

#define NB 16
#define NC 80
#define NA 21824
#define NM 1000
#define NHBINS 2048        // key>>51: sign(0)+exp8+mant4; scores<1 => prefix<=2031
#define CANDCAP 4096

// ws layout (bytes)
#define OFF_KEYS     0ul           // 16*21824*8   = 2,793,472
#define OFF_CLSV     2793472ul     // 16*21824*4   = 1,396,736
#define OFF_HIST     4190208ul     // 16*2048*4    = 131,072
#define OFF_CANDCNT  4321280ul     // 64
#define OFF_MAXB     4321344ul     // 64
#define OFF_CANDS    4321408ul     // 16*4096*8    = 524,288
#define OFF_TOPSCORE 4845696ul     // 64,000
#define OFF_TOPCLS   4909696ul     // 64,000
#define OFF_TOPBOX   4973696ul     // 256,000 -> end 5,229,696
                                   // (mask now lives in k_tail's LDS only)

__device__ __forceinline__ float sigm(float x) { return 1.0f / (1.0f + expf(-x)); }

// ---------------- Kernel 1: per-anchor score/key/class + LDS histogram ----------------
// 4-deep rotating prefetch (~50 VGPR) + 14 KB LDS + launch_bounds(256,6):
// 6 blocks/CU * 256 CUs = 1536 >= 1376 grid => ALL blocks co-resident, no tail.
__global__ __launch_bounds__(256, 6) void k_score(
    const float* __restrict__ cls3, const float* __restrict__ cnt3,
    const float* __restrict__ cls4, const float* __restrict__ cnt4,
    const float* __restrict__ cls5, const float* __restrict__ cnt5,
    const float* __restrict__ cls6, const float* __restrict__ cnt6,
    const float* __restrict__ cls7, const float* __restrict__ cnt7,
    unsigned long long* __restrict__ keys,
    float* __restrict__ clsv, unsigned int* __restrict__ hist)
{
    __shared__ unsigned int histpk[NHBINS / 2];   // 4 KB packed u16 counts
    __shared__ float lm[4 * 64 * 4];
    __shared__ int   lam[4 * 64 * 4];
    __shared__ float cm[256];
    __shared__ int   cam[256];
    const int b = blockIdx.y;
    const int tid = threadIdx.x;
    const int a = tid & 63, s = tid >> 6;
    const int g4 = blockIdx.x * 64 + a;

    for (int i = tid; i < NHBINS / 2; i += 256) histpk[i] = 0u;

    if (g4 < (NA >> 2)) {
        const int n = g4 << 2;
        const float* clsP; int off, logW;
        if      (n < 16384) { clsP = cls3; off = 0;     logW = 7; }
        else if (n < 20480) { clsP = cls4; off = 16384; logW = 6; }
        else if (n < 21504) { clsP = cls5; off = 20480; logW = 5; }
        else if (n < 21760) { clsP = cls6; off = 21504; logW = 4; }
        else                { clsP = cls7; off = 21760; logW = 3; }
        const int HW4 = 1 << (2 * logW - 2);
        const int l4 = (n - off) >> 2;
        const float4* cp = (const float4*)clsP + (size_t)b * NC * HW4 + l4;
        const int c0 = s * 20;
        float4 buf[4];
#pragma unroll
        for (int u = 0; u < 4; u++) buf[u] = cp[(size_t)(c0 + u) * HW4];
        float m[4] = { -3.402823466e+38f, -3.402823466e+38f, -3.402823466e+38f, -3.402823466e+38f };
        int am[4] = { c0, c0, c0, c0 };
#pragma unroll
        for (int u = 0; u < 20; u++) {
            float4 vv = buf[u & 3];
            if (u + 4 < 20) buf[u & 3] = cp[(size_t)(c0 + u + 4) * HW4];
            const int c = c0 + u;
            if (vv.x > m[0]) { m[0] = vv.x; am[0] = c; }   // strict > keeps first max (np.argmax)
            if (vv.y > m[1]) { m[1] = vv.y; am[1] = c; }
            if (vv.z > m[2]) { m[2] = vv.z; am[2] = c; }
            if (vv.w > m[3]) { m[3] = vv.w; am[3] = c; }
        }
#pragma unroll
        for (int k = 0; k < 4; k++) { lm[tid * 4 + k] = m[k]; lam[tid * 4 + k] = am[k]; }
    }
    __syncthreads();
    if (tid < 64 && (blockIdx.x * 64 + tid) < (NA >> 2)) {
        float M[4]; int AM[4];
#pragma unroll
        for (int k = 0; k < 4; k++) { M[k] = lm[tid * 4 + k]; AM[k] = lam[tid * 4 + k]; }
        for (int s2 = 1; s2 < 4; s2++) {
#pragma unroll
            for (int k = 0; k < 4; k++) {
                float vv = lm[(s2 * 64 + tid) * 4 + k];
                if (vv > M[k]) { M[k] = vv; AM[k] = lam[(s2 * 64 + tid) * 4 + k]; }
            }
        }
#pragma unroll
        for (int k = 0; k < 4; k++) { cm[tid * 4 + k] = M[k]; cam[tid * 4 + k] = AM[k]; }
    }
    __syncthreads();
    const int n2 = blockIdx.x * 256 + tid;
    if (n2 < NA) {
        const float* cntP; int off, logW;
        if      (n2 < 16384) { cntP = cnt3; off = 0;     logW = 7; }
        else if (n2 < 20480) { cntP = cnt4; off = 16384; logW = 6; }
        else if (n2 < 21504) { cntP = cnt5; off = 20480; logW = 5; }
        else if (n2 < 21760) { cntP = cnt6; off = 21504; logW = 4; }
        else                 { cntP = cnt7; off = 21760; logW = 3; }
        const int HW = 1 << (2 * logW);
        const int local = n2 - off;
        float cn = cntP[(size_t)b * HW + local];
        float M = cm[tid]; int AM = cam[tid];
        float sc = sqrtf(sigm(M) * sigm(cn));
        unsigned long long key = ((unsigned long long)__float_as_uint(sc) << 32)
                               | (unsigned int)(~(unsigned int)n2);
        keys[(size_t)b * NA + n2] = key;
        unsigned int bin = (unsigned int)(key >> 51);   // < 2048 for score in (0,1)
        atomicAdd(&histpk[bin >> 1], (bin & 1u) ? 0x10000u : 1u);   // LDS atomic
        clsv[(size_t)b * NA + n2] = (float)(AM + 1);
    }
    __syncthreads();
    unsigned int* gh = hist + b * NHBINS;
    for (int i = tid; i < NHBINS / 2; i += 256) {
        unsigned int pk = histpk[i];
        if (pk) {
            unsigned int lo = pk & 0xFFFFu, hi = pk >> 16;
            if (lo) atomicAdd(&gh[2 * i], lo);
            if (hi) atomicAdd(&gh[2 * i + 1], hi);
        }
    }
}

// ---------------- Kernel 2: boundary bin + compact candidates (block-aggregated) ----------------
__global__ __launch_bounds__(256) void k_compact(
    const unsigned long long* __restrict__ keys, const unsigned int* __restrict__ hist,
    unsigned int* __restrict__ candcnt, unsigned long long* __restrict__ cands)
{
    __shared__ int part1[256];
    __shared__ int part2[8];
    __shared__ int sBoundary;
    __shared__ unsigned int lcount;
    __shared__ unsigned int lbase;
    const int b = blockIdx.y;
    const int tid = threadIdx.x;
    const unsigned int* h = hist + b * NHBINS;
    int sum = 0;
    for (int i = 0; i < 8; i++) sum += (int)h[tid * 8 + i];
    part1[tid] = sum;
    if (tid == 0) lcount = 0u;
    __syncthreads();
    if (tid < 8) { int s2 = 0; for (int t = 0; t < 32; t++) s2 += part1[tid * 32 + t]; part2[tid] = s2; }
    __syncthreads();
    if (tid == 0) {
        int acc = 0, sc;
        for (sc = 7; sc > 0; sc--) { if (acc + part2[sc] >= NM) break; acc += part2[sc]; }
        int t;
        for (t = sc * 32 + 31; t > sc * 32; t--) { if (acc + part1[t] >= NM) break; acc += part1[t]; }
        int bin;
        for (bin = t * 8 + 7; bin > t * 8; bin--) { if (acc + (int)h[bin] >= NM) break; acc += (int)h[bin]; }
        sBoundary = bin;
    }
    __syncthreads();
    const unsigned int boundary = (unsigned int)sBoundary;
    unsigned long long hk[4]; unsigned int hslot[4]; int nh = 0;
    for (int nn = blockIdx.x * 256 + tid; nn < NA; nn += 22 * 256) {
        unsigned long long key = keys[(size_t)b * NA + nn];
        if ((unsigned int)(key >> 51) >= boundary) {
            hslot[nh] = atomicAdd(&lcount, 1u);   // LDS atomic
            hk[nh] = key;
            nh++;
        }
    }
    __syncthreads();
    if (tid == 0) lbase = atomicAdd(&candcnt[b], lcount);   // ONE global atomic per block
    __syncthreads();
    const unsigned int base = lbase;
    for (int t = 0; t < nh; t++) {
        unsigned int pos = base + hslot[t];
        if (pos < CANDCAP) cands[(size_t)b * CANDCAP + pos] = hk[t];
    }
}

// ---------------- Kernel 3: exact rank by counting; recompute box from reg gathers ----------------
__global__ __launch_bounds__(256) void k_rank(
    const unsigned long long* __restrict__ cands, const unsigned int* __restrict__ candcnt,
    const float* __restrict__ clsv,
    const float* __restrict__ reg3, const float* __restrict__ reg4, const float* __restrict__ reg5,
    const float* __restrict__ reg6, const float* __restrict__ reg7,
    float* __restrict__ topscore, float* __restrict__ topcls,
    float4* __restrict__ topbox, unsigned int* __restrict__ maxbEnc)
{
    __shared__ unsigned long long sbuf[CANDCAP];
    __shared__ unsigned int redmax[256];
    const int b = blockIdx.y;
    int cnt = (int)candcnt[b]; if (cnt > CANDCAP) cnt = CANDCAP;
    const int base = blockIdx.x * 256;
    if (base >= cnt) return;   // uniform across block
    const int tid = threadIdx.x;
    for (int i = tid; i < cnt; i += 256) sbuf[i] = cands[(size_t)b * CANDCAP + i];
    __syncthreads();
    const int idx = base + tid;
    unsigned int enc = 0;
    if (idx < cnt) {
        const unsigned long long key = sbuf[idx];
        const unsigned int ai = ~(unsigned int)key;
        const float* regP; int off, W, logW, st;
        if      (ai < 16384) { regP = reg3; off = 0;     W = 128; logW = 7; st = 8;   }
        else if (ai < 20480) { regP = reg4; off = 16384; W = 64;  logW = 6; st = 16;  }
        else if (ai < 21504) { regP = reg5; off = 20480; W = 32;  logW = 5; st = 32;  }
        else if (ai < 21760) { regP = reg6; off = 21504; W = 16;  logW = 4; st = 64;  }
        else                 { regP = reg7; off = 21760; W = 8;   logW = 3; st = 128; }
        const int local = (int)ai - off;
        const int HW = 1 << (2 * logW);
        const float* rp = regP + (size_t)b * 4 * HW + local;
        float r0 = rp[0], r1 = rp[HW], r2 = rp[2 * HW], r3 = rp[3 * HW];
        float cv = clsv[(size_t)b * NA + ai];
        int rank = 0;
        int j = 0;
        for (; j + 4 <= cnt; j += 4) {
            rank += (sbuf[j] > key) + (sbuf[j+1] > key) + (sbuf[j+2] > key) + (sbuf[j+3] > key);
        }
        for (; j < cnt; j++) rank += (sbuf[j] > key);
        if (rank < NM) {
            const float hs = (float)(st >> 1);
            float cx = (float)((local & (W - 1)) * st) + hs;
            float cy = (float)((local >> logW) * st) + hs;
            float4 bx = make_float4(cx - r0, cy - r1, cx + r2, cy + r3);
            topscore[b * NM + rank] = __uint_as_float((unsigned int)(key >> 32));
            topcls[b * NM + rank] = cv;
            topbox[b * NM + rank] = bx;
            float mx = fmaxf(fmaxf(bx.x, bx.y), fmaxf(bx.z, bx.w));
            unsigned int ub = __float_as_uint(mx);
            enc = (ub & 0x80000000u) ? ~ub : (ub | 0x80000000u);  // ordered-uint encoding
        }
    }
    redmax[tid] = enc;
    __syncthreads();
    for (int sgap = 128; sgap > 0; sgap >>= 1) {
        if (tid < sgap) { unsigned int o = redmax[tid + sgap]; if (o > redmax[tid]) redmax[tid] = o; }
        __syncthreads();
    }
    if (tid == 0 && redmax[0]) atomicMax(&maxbEnc[b], redmax[0]);
}

// ---------------- Kernel 4: fused IoU-mask + word-serial sweep + masked output ----------------
// One block per image, 1024 threads (16 waves). Mask built directly in LDS (125 KB);
// no global mask traffic. Sweep = R5's proven word-serial scalar closure.
__global__ __launch_bounds__(1024, 1) void k_tail(
    const float4* __restrict__ topbox, const float* __restrict__ topcls,
    const float* __restrict__ topscore, const unsigned int* __restrict__ maxbEnc,
    float* __restrict__ out)
{
    __shared__ unsigned long long smask[16 * NM];   // 125 KB, [word][row]
    __shared__ float4 sB[NM];                       // 16 KB shifted boxes
    __shared__ float  sA[NM];                       // 4 KB areas
    __shared__ unsigned long long lremv[16];
    const int b = blockIdx.x;
    const int tid = threadIdx.x;
    const int j = tid & 63, q = tid >> 6;

    unsigned int enc = maxbEnc[b];
    unsigned int ub = (enc & 0x80000000u) ? (enc & 0x7FFFFFFFu) : ~enc;
    const float mp1 = __fadd_rn(__uint_as_float(ub), 1.0f);

    float myscore = 0.f, mycls = 0.f;
    float4 mybox = make_float4(0.f, 0.f, 0.f, 0.f);
    if (tid < NM) {
        myscore = topscore[b * NM + tid];
        mycls = topcls[b * NM + tid];
        mybox = topbox[b * NM + tid];
        float off = __fmul_rn(mycls, mp1);
        float4 f = make_float4(__fadd_rn(mybox.x, off), __fadd_rn(mybox.y, off),
                               __fadd_rn(mybox.z, off), __fadd_rn(mybox.w, off));
        sB[tid] = f;
        sA[tid] = __fmul_rn(__fadd_rn(__fsub_rn(f.z, f.x), 1.0f),
                            __fadd_rn(__fsub_rn(f.w, f.y), 1.0f));
    }
    if (tid < 16) lremv[tid] = 0ULL;
    __syncthreads();

    // build mask in LDS + seed low-score suppression
    for (int t = tid; t < 16 * NM; t += 1024) {
        int w = t / NM, i = t - w * NM;
        float4 bi = sB[i]; float ai = sA[i];
        unsigned long long bits = 0ULL;
        int j0 = w << 6;
        int jstart = (j0 > i + 1) ? j0 : i + 1;
        int jend = (j0 + 64 < NM) ? j0 + 64 : NM;
        for (int jj = jstart; jj < jend; jj++) {
            float4 bj = sB[jj];
            float xx1 = fmaxf(bi.x, bj.x);
            float yy1 = fmaxf(bi.y, bj.y);
            float xx2 = fminf(bi.z, bj.z);
            float yy2 = fminf(bi.w, bj.w);
            float iw = fmaxf(__fsub_rn(xx2, xx1), 0.0f);
            float ih = fmaxf(__fsub_rn(yy2, yy1), 0.0f);
            float inter = __fmul_rn(iw, ih);
            float denom = __fsub_rn(__fadd_rn(ai, sA[jj]), inter);
            float iou = inter / denom;
            if (iou > 0.6f) bits |= (1ULL << (jj - j0));
        }
        smask[w * NM + i] = bits;
    }
    if (tid < NM && !(myscore >= 0.05f)) atomicOr(&lremv[tid >> 6], 1ULL << (tid & 63));

    for (int w = 0; w < 16; w++) {
        __syncthreads();   // prior word's cross-word atomics + mask/seeds visible
        const int row = w * 64 + j;
        unsigned long long D = (row < NM) ? smask[w * NM + row] : 0ULL;
        unsigned int dlo = (unsigned int)D, dhi = (unsigned int)(D >> 32);
        unsigned long long sv = lremv[w];
        unsigned int slo = __builtin_amdgcn_readfirstlane((unsigned int)sv);
        unsigned int shi = __builtin_amdgcn_readfirstlane((unsigned int)(sv >> 32));
        unsigned long long s = ((unsigned long long)shi << 32) | slo;
#pragma unroll
        for (int bb = 0; bb < 64; bb++) {
            unsigned int rlo = __builtin_amdgcn_readlane(dlo, bb);
            unsigned int rhi = __builtin_amdgcn_readlane(dhi, bb);
            unsigned long long rowv = ((unsigned long long)rhi << 32) | rlo;
            unsigned long long t = s | rowv;
            s = ((s >> bb) & 1ULL) ? s : t;
        }
        if (tid == 0) lremv[w] = s;
        const unsigned long long kw = ~s;
        if ((kw >> j) & 1ULL) {
            for (int k = w + 1 + q; k < 16; k += 16) {
                unsigned long long v = (row < NM) ? smask[k * NM + row] : 0ULL;
                if (v) atomicOr(&lremv[k], v);
            }
        }
    }
    __syncthreads();

    if (tid < NM) {
        bool keep = !((lremv[tid >> 6] >> (tid & 63)) & 1ULL);
        float kf = keep ? 1.0f : 0.0f;
        out[b * NM + tid] = myscore * kf;
        out[NB * NM + b * NM + tid] = mycls * kf;
        ((float4*)(out + 2 * NB * NM))[b * NM + tid] =
            make_float4(mybox.x * kf, mybox.y * kf, mybox.z * kf, mybox.w * kf);
    }
}

extern "C" void kernel_launch(void* const* d_in, const int* in_sizes, int n_in,
                              void* d_out, int out_size, void* d_ws, size_t ws_size,
                              hipStream_t stream) {
    const float* cls3 = (const float*)d_in[0];
    const float* cnt3 = (const float*)d_in[1];
    const float* reg3 = (const float*)d_in[2];
    const float* cls4 = (const float*)d_in[3];
    const float* cnt4 = (const float*)d_in[4];
    const float* reg4 = (const float*)d_in[5];
    const float* cls5 = (const float*)d_in[6];
    const float* cnt5 = (const float*)d_in[7];
    const float* reg5 = (const float*)d_in[8];
    const float* cls6 = (const float*)d_in[9];
    const float* cnt6 = (const float*)d_in[10];
    const float* reg6 = (const float*)d_in[11];
    const float* cls7 = (const float*)d_in[12];
    const float* cnt7 = (const float*)d_in[13];
    const float* reg7 = (const float*)d_in[14];

    char* ws = (char*)d_ws;
    unsigned long long* keys   = (unsigned long long*)(ws + OFF_KEYS);
    float*              clsv   = (float*)(ws + OFF_CLSV);
    unsigned int*       hist   = (unsigned int*)(ws + OFF_HIST);
    unsigned int*       candcnt= (unsigned int*)(ws + OFF_CANDCNT);
    unsigned int*       maxbE  = (unsigned int*)(ws + OFF_MAXB);
    unsigned long long* cands  = (unsigned long long*)(ws + OFF_CANDS);
    float*              topsc  = (float*)(ws + OFF_TOPSCORE);
    float*              topcl  = (float*)(ws + OFF_TOPCLS);
    float4*             topbx  = (float4*)(ws + OFF_TOPBOX);

    // zero hist + candcnt + maxb (ws is poisoned 0xAA before every launch)
    hipMemsetAsync(ws + OFF_HIST, 0, (size_t)(NB * NHBINS * 4 + 128), stream);

    dim3 g1(86, NB);   // 86*64 anchor-quads >= 5456
    k_score<<<g1, 256, 0, stream>>>(cls3, cnt3, cls4, cnt4, cls5, cnt5,
                                    cls6, cnt6, cls7, cnt7,
                                    keys, clsv, hist);
    dim3 g2(22, NB);
    k_compact<<<g2, 256, 0, stream>>>(keys, hist, candcnt, cands);
    dim3 g3(CANDCAP / 256, NB);
    k_rank<<<g3, 256, 0, stream>>>(cands, candcnt, clsv, reg3, reg4, reg5, reg6, reg7,
                                   topsc, topcl, topbx, maxbE);
    k_tail<<<NB, 1024, 0, stream>>>(topbx, topcl, topsc, maxbE, (float*)d_out);
}

// Round 8
// 264.947 us; speedup vs baseline: 1.5585x; 1.5585x over previous
//
#include <hip/hip_runtime.h>
#include <hip/hip_bf16.h>
#include <math.h>

#define NB 16
#define NC 80
#define NA 21824
#define NM 1000
#define NHBINS 2048        // key>>51: sign(0)+exp8+mant4; scores<1 => prefix<=2031
#define CANDCAP 4096

// ws layout (bytes)
#define OFF_KEYS     0ul           // 16*21824*8   = 2,793,472
#define OFF_CLSV     2793472ul     // 16*21824*4   = 1,396,736
#define OFF_HIST     4190208ul     // 16*2048*4    = 131,072
#define OFF_CANDCNT  4321280ul     // 64
#define OFF_MAXB     4321344ul     // 64
#define OFF_CANDS    4321408ul     // 16*4096*8    = 524,288
#define OFF_TOPSCORE 4845696ul     // 64,000
#define OFF_TOPCLS   4909696ul     // 64,000
#define OFF_TOPBOX   4973696ul     // 256,000
#define OFF_MASK     5229696ul     // 16*16*1000*8 = 2,048,000 -> end 7,277,696
                                   // mask layout: [b][word][row] (row fast)

__device__ __forceinline__ float sigm(float x) { return 1.0f / (1.0f + expf(-x)); }

// ---------------- Kernel 1: per-anchor score/key/class + LDS histogram ----------------
__global__ __launch_bounds__(256, 6) void k_score(
    const float* __restrict__ cls3, const float* __restrict__ cnt3,
    const float* __restrict__ cls4, const float* __restrict__ cnt4,
    const float* __restrict__ cls5, const float* __restrict__ cnt5,
    const float* __restrict__ cls6, const float* __restrict__ cnt6,
    const float* __restrict__ cls7, const float* __restrict__ cnt7,
    unsigned long long* __restrict__ keys,
    float* __restrict__ clsv, unsigned int* __restrict__ hist)
{
    __shared__ unsigned int histpk[NHBINS / 2];   // 4 KB packed u16 counts
    __shared__ float lm[4 * 64 * 4];
    __shared__ int   lam[4 * 64 * 4];
    __shared__ float cm[256];
    __shared__ int   cam[256];
    const int b = blockIdx.y;
    const int tid = threadIdx.x;
    const int a = tid & 63, s = tid >> 6;
    const int g4 = blockIdx.x * 64 + a;

    for (int i = tid; i < NHBINS / 2; i += 256) histpk[i] = 0u;

    if (g4 < (NA >> 2)) {
        const int n = g4 << 2;
        const float* clsP; int off, logW;
        if      (n < 16384) { clsP = cls3; off = 0;     logW = 7; }
        else if (n < 20480) { clsP = cls4; off = 16384; logW = 6; }
        else if (n < 21504) { clsP = cls5; off = 20480; logW = 5; }
        else if (n < 21760) { clsP = cls6; off = 21504; logW = 4; }
        else                { clsP = cls7; off = 21760; logW = 3; }
        const int HW4 = 1 << (2 * logW - 2);
        const int l4 = (n - off) >> 2;
        const float4* cp = (const float4*)clsP + (size_t)b * NC * HW4 + l4;
        const int c0 = s * 20;
        float4 buf[4];
#pragma unroll
        for (int u = 0; u < 4; u++) buf[u] = cp[(size_t)(c0 + u) * HW4];
        float m[4] = { -3.402823466e+38f, -3.402823466e+38f, -3.402823466e+38f, -3.402823466e+38f };
        int am[4] = { c0, c0, c0, c0 };
#pragma unroll
        for (int u = 0; u < 20; u++) {
            float4 vv = buf[u & 3];
            if (u + 4 < 20) buf[u & 3] = cp[(size_t)(c0 + u + 4) * HW4];
            const int c = c0 + u;
            if (vv.x > m[0]) { m[0] = vv.x; am[0] = c; }   // strict > keeps first max (np.argmax)
            if (vv.y > m[1]) { m[1] = vv.y; am[1] = c; }
            if (vv.z > m[2]) { m[2] = vv.z; am[2] = c; }
            if (vv.w > m[3]) { m[3] = vv.w; am[3] = c; }
        }
#pragma unroll
        for (int k = 0; k < 4; k++) { lm[tid * 4 + k] = m[k]; lam[tid * 4 + k] = am[k]; }
    }
    __syncthreads();
    if (tid < 64 && (blockIdx.x * 64 + tid) < (NA >> 2)) {
        float M[4]; int AM[4];
#pragma unroll
        for (int k = 0; k < 4; k++) { M[k] = lm[tid * 4 + k]; AM[k] = lam[tid * 4 + k]; }
        for (int s2 = 1; s2 < 4; s2++) {
#pragma unroll
            for (int k = 0; k < 4; k++) {
                float vv = lm[(s2 * 64 + tid) * 4 + k];
                if (vv > M[k]) { M[k] = vv; AM[k] = lam[(s2 * 64 + tid) * 4 + k]; }
            }
        }
#pragma unroll
        for (int k = 0; k < 4; k++) { cm[tid * 4 + k] = M[k]; cam[tid * 4 + k] = AM[k]; }
    }
    __syncthreads();
    const int n2 = blockIdx.x * 256 + tid;
    if (n2 < NA) {
        const float* cntP; int off, logW;
        if      (n2 < 16384) { cntP = cnt3; off = 0;     logW = 7; }
        else if (n2 < 20480) { cntP = cnt4; off = 16384; logW = 6; }
        else if (n2 < 21504) { cntP = cnt5; off = 20480; logW = 5; }
        else if (n2 < 21760) { cntP = cnt6; off = 21504; logW = 4; }
        else                 { cntP = cnt7; off = 21760; logW = 3; }
        const int HW = 1 << (2 * logW);
        const int local = n2 - off;
        float cn = cntP[(size_t)b * HW + local];
        float M = cm[tid]; int AM = cam[tid];
        float sc = sqrtf(sigm(M) * sigm(cn));
        unsigned long long key = ((unsigned long long)__float_as_uint(sc) << 32)
                               | (unsigned int)(~(unsigned int)n2);
        keys[(size_t)b * NA + n2] = key;
        unsigned int bin = (unsigned int)(key >> 51);   // < 2048 for score in (0,1)
        atomicAdd(&histpk[bin >> 1], (bin & 1u) ? 0x10000u : 1u);   // LDS atomic
        clsv[(size_t)b * NA + n2] = (float)(AM + 1);
    }
    __syncthreads();
    unsigned int* gh = hist + b * NHBINS;
    for (int i = tid; i < NHBINS / 2; i += 256) {
        unsigned int pk = histpk[i];
        if (pk) {
            unsigned int lo = pk & 0xFFFFu, hi = pk >> 16;
            if (lo) atomicAdd(&gh[2 * i], lo);
            if (hi) atomicAdd(&gh[2 * i + 1], hi);
        }
    }
}

// ---------------- Kernel 2: boundary bin + compact candidates (block-aggregated) ----------------
__global__ __launch_bounds__(256) void k_compact(
    const unsigned long long* __restrict__ keys, const unsigned int* __restrict__ hist,
    unsigned int* __restrict__ candcnt, unsigned long long* __restrict__ cands)
{
    __shared__ int part1[256];
    __shared__ int part2[8];
    __shared__ int sBoundary;
    __shared__ unsigned int lcount;
    __shared__ unsigned int lbase;
    const int b = blockIdx.y;
    const int tid = threadIdx.x;
    const unsigned int* h = hist + b * NHBINS;
    int sum = 0;
    for (int i = 0; i < 8; i++) sum += (int)h[tid * 8 + i];
    part1[tid] = sum;
    if (tid == 0) lcount = 0u;
    __syncthreads();
    if (tid < 8) { int s2 = 0; for (int t = 0; t < 32; t++) s2 += part1[tid * 32 + t]; part2[tid] = s2; }
    __syncthreads();
    if (tid == 0) {
        int acc = 0, sc;
        for (sc = 7; sc > 0; sc--) { if (acc + part2[sc] >= NM) break; acc += part2[sc]; }
        int t;
        for (t = sc * 32 + 31; t > sc * 32; t--) { if (acc + part1[t] >= NM) break; acc += part1[t]; }
        int bin;
        for (bin = t * 8 + 7; bin > t * 8; bin--) { if (acc + (int)h[bin] >= NM) break; acc += (int)h[bin]; }
        sBoundary = bin;
    }
    __syncthreads();
    const unsigned int boundary = (unsigned int)sBoundary;
    unsigned long long hk[4]; unsigned int hslot[4]; int nh = 0;
    for (int nn = blockIdx.x * 256 + tid; nn < NA; nn += 22 * 256) {
        unsigned long long key = keys[(size_t)b * NA + nn];
        if ((unsigned int)(key >> 51) >= boundary) {
            hslot[nh] = atomicAdd(&lcount, 1u);   // LDS atomic
            hk[nh] = key;
            nh++;
        }
    }
    __syncthreads();
    if (tid == 0) lbase = atomicAdd(&candcnt[b], lcount);   // ONE global atomic per block
    __syncthreads();
    const unsigned int base = lbase;
    for (int t = 0; t < nh; t++) {
        unsigned int pos = base + hslot[t];
        if (pos < CANDCAP) cands[(size_t)b * CANDCAP + pos] = hk[t];
    }
}

// ---------------- Kernel 3: exact rank by counting; recompute box from reg gathers ----------------
__global__ __launch_bounds__(256) void k_rank(
    const unsigned long long* __restrict__ cands, const unsigned int* __restrict__ candcnt,
    const float* __restrict__ clsv,
    const float* __restrict__ reg3, const float* __restrict__ reg4, const float* __restrict__ reg5,
    const float* __restrict__ reg6, const float* __restrict__ reg7,
    float* __restrict__ topscore, float* __restrict__ topcls,
    float4* __restrict__ topbox, unsigned int* __restrict__ maxbEnc)
{
    __shared__ unsigned long long sbuf[CANDCAP];
    __shared__ unsigned int redmax[256];
    const int b = blockIdx.y;
    int cnt = (int)candcnt[b]; if (cnt > CANDCAP) cnt = CANDCAP;
    const int base = blockIdx.x * 256;
    if (base >= cnt) return;   // uniform across block
    const int tid = threadIdx.x;
    for (int i = tid; i < cnt; i += 256) sbuf[i] = cands[(size_t)b * CANDCAP + i];
    __syncthreads();
    const int idx = base + tid;
    unsigned int enc = 0;
    if (idx < cnt) {
        const unsigned long long key = sbuf[idx];
        const unsigned int ai = ~(unsigned int)key;
        const float* regP; int off, W, logW, st;
        if      (ai < 16384) { regP = reg3; off = 0;     W = 128; logW = 7; st = 8;   }
        else if (ai < 20480) { regP = reg4; off = 16384; W = 64;  logW = 6; st = 16;  }
        else if (ai < 21504) { regP = reg5; off = 20480; W = 32;  logW = 5; st = 32;  }
        else if (ai < 21760) { regP = reg6; off = 21504; W = 16;  logW = 4; st = 64;  }
        else                 { regP = reg7; off = 21760; W = 8;   logW = 3; st = 128; }
        const int local = (int)ai - off;
        const int HW = 1 << (2 * logW);
        const float* rp = regP + (size_t)b * 4 * HW + local;
        float r0 = rp[0], r1 = rp[HW], r2 = rp[2 * HW], r3 = rp[3 * HW];
        float cv = clsv[(size_t)b * NA + ai];
        int rank = 0;
        int j = 0;
        for (; j + 4 <= cnt; j += 4) {
            rank += (sbuf[j] > key) + (sbuf[j+1] > key) + (sbuf[j+2] > key) + (sbuf[j+3] > key);
        }
        for (; j < cnt; j++) rank += (sbuf[j] > key);
        if (rank < NM) {
            const float hs = (float)(st >> 1);
            float cx = (float)((local & (W - 1)) * st) + hs;
            float cy = (float)((local >> logW) * st) + hs;
            float4 bx = make_float4(cx - r0, cy - r1, cx + r2, cy + r3);
            topscore[b * NM + rank] = __uint_as_float((unsigned int)(key >> 32));
            topcls[b * NM + rank] = cv;
            topbox[b * NM + rank] = bx;
            float mx = fmaxf(fmaxf(bx.x, bx.y), fmaxf(bx.z, bx.w));
            unsigned int ub = __float_as_uint(mx);
            enc = (ub & 0x80000000u) ? ~ub : (ub | 0x80000000u);  // ordered-uint encoding
        }
    }
    redmax[tid] = enc;
    __syncthreads();
    for (int sgap = 128; sgap > 0; sgap >>= 1) {
        if (tid < sgap) { unsigned int o = redmax[tid + sgap]; if (o > redmax[tid]) redmax[tid] = o; }
        __syncthreads();
    }
    if (tid == 0 && redmax[0]) atomicMax(&maxbEnc[b], redmax[0]);
}

// ---------------- Kernel 4: suppression bitmask, layout mask[b][word][row] ----------------
// 1008 blocks: IoU build is compute-heavy (~8M IoUs total) and must stay wide.
__global__ __launch_bounds__(256) void k_iou(
    const float4* __restrict__ topbox, const float* __restrict__ topcls,
    const unsigned int* __restrict__ maxbEnc, unsigned long long* __restrict__ maskArr)
{
    __shared__ float4 sB[NM];
    __shared__ float sA[NM];
    const int b = blockIdx.y;
    const int tid = threadIdx.x;
    unsigned int enc = maxbEnc[b];
    unsigned int ub = (enc & 0x80000000u) ? (enc & 0x7FFFFFFFu) : ~enc;
    const float mp1 = __fadd_rn(__uint_as_float(ub), 1.0f);
    for (int r = tid; r < NM; r += 256) {
        float4 f = topbox[b * NM + r];
        float off = __fmul_rn(topcls[b * NM + r], mp1);
        f.x = __fadd_rn(f.x, off); f.y = __fadd_rn(f.y, off);
        f.z = __fadd_rn(f.z, off); f.w = __fadd_rn(f.w, off);
        sB[r] = f;
        sA[r] = __fmul_rn(__fadd_rn(__fsub_rn(f.z, f.x), 1.0f),
                          __fadd_rn(__fsub_rn(f.w, f.y), 1.0f));
    }
    __syncthreads();
    int task = blockIdx.x * 256 + tid;
    if (task >= NM * 16) return;
    int w = task / NM, i = task - w * NM;
    float4 bi = sB[i]; float ai = sA[i];
    unsigned long long bits = 0ULL;
    int j0 = w << 6;
    int jstart = (j0 > i + 1) ? j0 : i + 1;
    int jend = (j0 + 64 < NM) ? j0 + 64 : NM;
    for (int j = jstart; j < jend; j++) {
        float4 bj = sB[j];
        float xx1 = fmaxf(bi.x, bj.x);
        float yy1 = fmaxf(bi.y, bj.y);
        float xx2 = fminf(bi.z, bj.z);
        float yy2 = fminf(bi.w, bj.w);
        float iw = fmaxf(__fsub_rn(xx2, xx1), 0.0f);
        float ih = fmaxf(__fsub_rn(yy2, yy1), 0.0f);
        float inter = __fmul_rn(iw, ih);
        float denom = __fsub_rn(__fadd_rn(ai, sA[j]), inter);
        float iou = inter / denom;
        if (iou > 0.6f) bits |= (1ULL << (j - j0));
    }
    maskArr[((size_t)b * 16 + w) * NM + i] = bits;
}

// ---------------- Kernel 5: LDS-resident word-serial sweep + masked output ----------------
__global__ __launch_bounds__(256) void k_nms_sweep(
    const unsigned long long* __restrict__ maskArr,
    const float* __restrict__ topscore, const float* __restrict__ topcls,
    const float4* __restrict__ topbox, float* __restrict__ out)
{
    __shared__ unsigned long long smask[16 * NM];   // 125 KB, [word][row]
    __shared__ unsigned long long lremv[16];
    const int b = blockIdx.x;
    const int tid = threadIdx.x;
    const int j = tid & 63, q = tid >> 6;
    const unsigned long long* gmask = maskArr + (size_t)b * (16 * NM);

    {
        const ulonglong2* src = (const ulonglong2*)gmask;
        ulonglong2* dst = (ulonglong2*)smask;
        for (int idx = tid; idx < 8 * NM; idx += 256) dst[idx] = src[idx];
    }
    if (tid < 16) lremv[tid] = 0ULL;
    __syncthreads();
    for (int r = tid; r < NM; r += 256) {
        float s = topscore[b * NM + r];
        if (!(s >= 0.05f)) atomicOr(&lremv[r >> 6], 1ULL << (r & 63));
    }

    for (int w = 0; w < 16; w++) {
        __syncthreads();   // prior word's cross-word atomics + seeds visible
        const int row = w * 64 + j;
        unsigned long long D = (row < NM) ? smask[w * NM + row] : 0ULL;
        unsigned int dlo = (unsigned int)D, dhi = (unsigned int)(D >> 32);
        unsigned long long sv = lremv[w];
        unsigned int slo = __builtin_amdgcn_readfirstlane((unsigned int)sv);
        unsigned int shi = __builtin_amdgcn_readfirstlane((unsigned int)(sv >> 32));
        unsigned long long s = ((unsigned long long)shi << 32) | slo;
#pragma unroll
        for (int bb = 0; bb < 64; bb++) {
            unsigned int rlo = __builtin_amdgcn_readlane(dlo, bb);
            unsigned int rhi = __builtin_amdgcn_readlane(dhi, bb);
            unsigned long long rowv = ((unsigned long long)rhi << 32) | rlo;
            unsigned long long t = s | rowv;
            s = ((s >> bb) & 1ULL) ? s : t;
        }
        if (tid == 0) lremv[w] = s;
        const unsigned long long kw = ~s;
        if ((kw >> j) & 1ULL) {
            for (int k = w + 1 + q; k < 16; k += 4) {
                unsigned long long v = (row < NM) ? smask[k * NM + row] : 0ULL;
                if (v) atomicOr(&lremv[k], v);
            }
        }
    }
    __syncthreads();

    for (int r = tid; r < NM; r += 256) {
        bool keep = !((lremv[r >> 6] >> (r & 63)) & 1ULL);
        float kf = keep ? 1.0f : 0.0f;
        out[b * NM + r] = topscore[b * NM + r] * kf;
        out[NB * NM + b * NM + r] = topcls[b * NM + r] * kf;
        float4 bx = topbox[b * NM + r];
        ((float4*)(out + 2 * NB * NM))[b * NM + r] = make_float4(bx.x * kf, bx.y * kf, bx.z * kf, bx.w * kf);
    }
}

extern "C" void kernel_launch(void* const* d_in, const int* in_sizes, int n_in,
                              void* d_out, int out_size, void* d_ws, size_t ws_size,
                              hipStream_t stream) {
    const float* cls3 = (const float*)d_in[0];
    const float* cnt3 = (const float*)d_in[1];
    const float* reg3 = (const float*)d_in[2];
    const float* cls4 = (const float*)d_in[3];
    const float* cnt4 = (const float*)d_in[4];
    const float* reg4 = (const float*)d_in[5];
    const float* cls5 = (const float*)d_in[6];
    const float* cnt5 = (const float*)d_in[7];
    const float* reg5 = (const float*)d_in[8];
    const float* cls6 = (const float*)d_in[9];
    const float* cnt6 = (const float*)d_in[10];
    const float* reg6 = (const float*)d_in[11];
    const float* cls7 = (const float*)d_in[12];
    const float* cnt7 = (const float*)d_in[13];
    const float* reg7 = (const float*)d_in[14];

    char* ws = (char*)d_ws;
    unsigned long long* keys   = (unsigned long long*)(ws + OFF_KEYS);
    float*              clsv   = (float*)(ws + OFF_CLSV);
    unsigned int*       hist   = (unsigned int*)(ws + OFF_HIST);
    unsigned int*       candcnt= (unsigned int*)(ws + OFF_CANDCNT);
    unsigned int*       maxbE  = (unsigned int*)(ws + OFF_MAXB);
    unsigned long long* cands  = (unsigned long long*)(ws + OFF_CANDS);
    float*              topsc  = (float*)(ws + OFF_TOPSCORE);
    float*              topcl  = (float*)(ws + OFF_TOPCLS);
    float4*             topbx  = (float4*)(ws + OFF_TOPBOX);
    unsigned long long* maskA  = (unsigned long long*)(ws + OFF_MASK);

    // zero hist + candcnt + maxb (ws is poisoned 0xAA before every launch)
    hipMemsetAsync(ws + OFF_HIST, 0, (size_t)(NB * NHBINS * 4 + 128), stream);

    dim3 g1(86, NB);   // 86*64 anchor-quads >= 5456
    k_score<<<g1, 256, 0, stream>>>(cls3, cnt3, cls4, cnt4, cls5, cnt5,
                                    cls6, cnt6, cls7, cnt7,
                                    keys, clsv, hist);
    dim3 g2(22, NB);
    k_compact<<<g2, 256, 0, stream>>>(keys, hist, candcnt, cands);
    dim3 g3(CANDCAP / 256, NB);
    k_rank<<<g3, 256, 0, stream>>>(cands, candcnt, clsv, reg3, reg4, reg5, reg6, reg7,
                                   topsc, topcl, topbx, maxbE);
    dim3 g4(63, NB);
    k_iou<<<g4, 256, 0, stream>>>(topbx, topcl, maxbE, maskA);
    k_nms_sweep<<<NB, 256, 0, stream>>>(maskA, topsc, topcl, topbx, (float*)d_out);
}